// Round 1
// baseline (250.840 us; speedup 1.0000x reference)
//
#include <hip/hip_runtime.h>
#include <math.h>

// Problem constants
static constexpr int NB  = 8;      // batch
static constexpr int NRC = 4096;   // rec atoms
static constexpr int NKP = 20;     // keypoints
static constexpr int NF  = 256;    // features
static constexpr int NHD = 4;      // heads
static constexpr int DD  = 256;    // per-head dim
static constexpr int NKH = NKP * NHD;  // 80 fused (k,h), kh = k*4+h
static constexpr int KCL = 8;      // k-closest
static constexpr int NT  = 32;     // row tiles in K3 (4096/128)
static constexpr float SCALE = 0.0625f; // 1/sqrt(256)

// workspace layout (float offsets)
static constexpr int FT_OFF = 0;
static constexpr int FT_CNT = NB * NKP * NHD * DD;   // 163840
static constexpr int M_OFF  = FT_OFF + FT_CNT;
static constexpr int M_CNT  = NB * NF * NKH;         // 163840
static constexpr int P_OFF  = M_OFF + M_CNT;
static constexpr int P_CNT  = NB * NT * NKH * 4;     // 81920

// K1: ft_dst[b,k,h,:] = h0_kp[b,k,:] @ W_src[:, h*256:(h+1)*256]
// grid: 8 * 10 * 4 = 320 blocks (b, k-pair, h), 256 threads (thread = d)
__global__ __launch_bounds__(256) void k1_ftdst(const float* __restrict__ h0,
                                                const float* __restrict__ W,
                                                float* __restrict__ ft) {
    int bx = blockIdx.x;
    int b = bx / 40;
    int rem = bx % 40;
    int kp = rem / 4;
    int h  = rem % 4;
    int k0 = kp * 2;
    __shared__ float2 hh[NF];
    int tid = threadIdx.x;
    hh[tid] = make_float2(h0[(b * NKP + k0) * NF + tid],
                          h0[(b * NKP + k0 + 1) * NF + tid]);
    __syncthreads();
    int d = tid;
    float a0 = 0.f, a1 = 0.f;
    const float* wp = W + h * DD + d;
#pragma unroll 8
    for (int g = 0; g < NF; ++g) {
        float w = wp[g * (NF * NHD)];
        float2 hv = hh[g];
        a0 += hv.x * w;
        a1 += hv.y * w;
    }
    ft[((b * NKP + k0) * NHD + h) * DD + d]     = a0;
    ft[((b * NKP + k0 + 1) * NHD + h) * DD + d] = a1;
}

// K2: M[b,f,kh] = (1/16) * sum_d W_src[f, h*256+d] * ft[b,k,h,d]
// grid 320 blocks (b, k-pair, h), 256 threads (thread = f)
__global__ __launch_bounds__(256) void k2_m(const float* __restrict__ ftg,
                                            const float* __restrict__ W,
                                            float* __restrict__ M) {
    int bx = blockIdx.x;
    int b = bx / 40;
    int rem = bx % 40;
    int kp = rem / 4;
    int h  = rem % 4;
    int k0 = kp * 2;
    __shared__ float2 ftl[DD];
    int tid = threadIdx.x;
    ftl[tid] = make_float2(ftg[((b * NKP + k0) * NHD + h) * DD + tid],
                           ftg[((b * NKP + k0 + 1) * NHD + h) * DD + tid]);
    __syncthreads();
    int f = tid;
    float m0 = 0.f, m1 = 0.f;
    const float4* wr = (const float4*)(W + f * (NF * NHD) + h * DD);
#pragma unroll 4
    for (int d4 = 0; d4 < DD / 4; ++d4) {
        float4 wv = wr[d4];
        float2 f0 = ftl[d4 * 4 + 0], f1 = ftl[d4 * 4 + 1];
        float2 f2 = ftl[d4 * 4 + 2], f3 = ftl[d4 * 4 + 3];
        m0 += wv.x * f0.x + wv.y * f1.x + wv.z * f2.x + wv.w * f3.x;
        m1 += wv.x * f0.y + wv.y * f1.y + wv.z * f2.y + wv.w * f3.y;
    }
    M[(b * NF + f) * NKH + (k0 * 4 + h)]       = m0 * SCALE;
    M[(b * NF + f) * NKH + ((k0 + 1) * 4 + h)] = m1 * SCALE;
}

// K3: scores A = h_rec[b] @ M[b]; e = exp(A); partial sums of (e, e*x, e*y, e*z)
// over 128-row tiles. grid 256 blocks (b, tile), 512 threads:
// q = tid>>7 selects 20 of the 80 kh columns, lrow = tid&127 is the row.
__global__ __launch_bounds__(512) void k3_scores(const float* __restrict__ hrec,
                                                 const float* __restrict__ xrec,
                                                 const float* __restrict__ M,
                                                 float* __restrict__ P) {
    int bx = blockIdx.x;
    int b = bx >> 5, t = bx & 31;
    int tid = threadIdx.x;
    int q = tid >> 7;
    int lrow = tid & 127;
    int r = t * 128 + lrow;

    float acc[20];
#pragma unroll
    for (int i = 0; i < 20; ++i) acc[i] = 0.f;

    const float4* hr = (const float4*)(hrec + (size_t)(b * NRC + r) * NF);
    const float* Mb = M + b * NF * NKH + q * 20;

    for (int f0 = 0; f0 < NF / 4; ++f0) {
        float4 hv = hr[f0];
#pragma unroll
        for (int j = 0; j < 4; ++j) {
            float hf = (j == 0) ? hv.x : (j == 1) ? hv.y : (j == 2) ? hv.z : hv.w;
            const float4* mr = (const float4*)(Mb + (f0 * 4 + j) * NKH);
#pragma unroll
            for (int c = 0; c < 5; ++c) {
                float4 mv = mr[c];
                acc[c * 4 + 0] += hf * mv.x;
                acc[c * 4 + 1] += hf * mv.y;
                acc[c * 4 + 2] += hf * mv.z;
                acc[c * 4 + 3] += hf * mv.w;
            }
        }
    }

    const float* xr = xrec + (size_t)(b * NRC + r) * 3;
    float xx = xr[0], xy = xr[1], xz = xr[2];

    __shared__ float red[8][20][4];
    int wav = tid >> 6;
    int lane = tid & 63;
#pragma unroll
    for (int kk = 0; kk < 20; ++kk) {
        float e = __expf(acc[kk]);
        float s0 = e, s1 = e * xx, s2 = e * xy, s3 = e * xz;
#pragma unroll
        for (int m = 1; m < 64; m <<= 1) {
            s0 += __shfl_xor(s0, m, 64);
            s1 += __shfl_xor(s1, m, 64);
            s2 += __shfl_xor(s2, m, 64);
            s3 += __shfl_xor(s3, m, 64);
        }
        if (lane == 0) {
            red[wav][kk][0] = s0; red[wav][kk][1] = s1;
            red[wav][kk][2] = s2; red[wav][kk][3] = s3;
        }
    }
    __syncthreads();
    if (tid < 320) {
        int qq = tid / 80;
        int rem = tid % 80;
        int khl = rem >> 2;
        int s = rem & 3;
        float v = red[qq * 2][khl][s] + red[qq * 2 + 1][khl][s];
        P[((b * NT + t) * NKH + qq * 20 + khl) * 4 + s] = v;
    }
}

// K4: per (b,k): kp_pos, top-8 nearest rec atoms, knn feature mean, MLP+SiLU, LN.
// grid 160 blocks, 256 threads.
__global__ __launch_bounds__(256) void k4_final(const float* __restrict__ hrec,
                                                const float* __restrict__ xrec,
                                                const float* __restrict__ P,
                                                const float* __restrict__ Wm,
                                                const float* __restrict__ bm,
                                                const float* __restrict__ gam,
                                                const float* __restrict__ bet,
                                                float* __restrict__ out) {
    int bx = blockIdx.x;
    int b = bx / NKP, k = bx % NKP;
    int tid = threadIdx.x;

    __shared__ float Sh[NHD][4];
    __shared__ float posl[3];
    __shared__ float d2[NRC];
    __shared__ float fin[NF + KCL];
    __shared__ int kidx[KCL];
    __shared__ float cd[4];
    __shared__ int ci[4];
    __shared__ float bcast[2];
    __shared__ float wred[4][2];

    if (tid < 16) {
        int h = tid >> 2, s = tid & 3;
        float a = 0.f;
#pragma unroll 4
        for (int t = 0; t < NT; ++t)
            a += P[((b * NT + t) * NKH + k * NHD + h) * 4 + s];
        Sh[h][s] = a;
    }
    __syncthreads();
    if (tid == 0) {
        for (int c = 0; c < 3; ++c) {
            float p = 0.f;
            for (int h = 0; h < NHD; ++h) p += Sh[h][c + 1] / Sh[h][0];
            p *= 0.25f;
            posl[c] = p;
            out[(b * NKP + k) * 3 + c] = p;
        }
    }
    __syncthreads();

    float px = posl[0], py = posl[1], pz = posl[2];
    for (int i = tid; i < NRC; i += 256) {
        const float* x = xrec + (size_t)(b * NRC + i) * 3;
        float dx = x[0] - px, dy = x[1] - py, dz = x[2] - pz;
        d2[i] = dx * dx + dy * dy + dz * dz;
    }
    __syncthreads();

    for (int j = 0; j < KCL; ++j) {
        float bd = 3.4e38f;
        int bi = -1;
        for (int i = tid; i < NRC; i += 256) {
            float v = d2[i];
            if (v < bd || (v == bd && i < bi)) { bd = v; bi = i; }
        }
        for (int off = 32; off >= 1; off >>= 1) {
            float od = __shfl_down(bd, off, 64);
            int oi = __shfl_down(bi, off, 64);
            if (od < bd || (od == bd && oi < bi)) { bd = od; bi = oi; }
        }
        if ((tid & 63) == 0) { cd[tid >> 6] = bd; ci[tid >> 6] = bi; }
        __syncthreads();
        if (tid == 0) {
            for (int w = 1; w < 4; ++w) {
                if (cd[w] < bd || (cd[w] == bd && ci[w] < bi)) { bd = cd[w]; bi = ci[w]; }
            }
            kidx[j] = bi;
            fin[NF + j] = sqrtf(bd);
            d2[bi] = 3.4e38f;
        }
        __syncthreads();
    }

    // knn feature mean
    float hm = 0.f;
#pragma unroll
    for (int j = 0; j < KCL; ++j)
        hm += hrec[(size_t)(b * NRC + kidx[j]) * NF + tid];
    fin[tid] = hm * 0.125f;
    __syncthreads();

    // MLP (264 -> 256) + SiLU
    float p = bm[tid];
#pragma unroll 4
    for (int i = 0; i < NF + KCL; ++i)
        p += fin[i] * Wm[i * NF + tid];
    float v = p / (1.f + __expf(-p));

    // LayerNorm over 256
    float s = v, sq = v * v;
#pragma unroll
    for (int m = 1; m < 64; m <<= 1) {
        s += __shfl_xor(s, m, 64);
        sq += __shfl_xor(sq, m, 64);
    }
    if ((tid & 63) == 0) { wred[tid >> 6][0] = s; wred[tid >> 6][1] = sq; }
    __syncthreads();
    if (tid == 0) {
        float ts = 0.f, tq = 0.f;
        for (int w = 0; w < 4; ++w) { ts += wred[w][0]; tq += wred[w][1]; }
        float mu = ts / 256.f;
        float var = tq / 256.f - mu * mu;
        bcast[0] = mu;
        bcast[1] = rsqrtf(var + 1e-5f);
    }
    __syncthreads();
    float o = (v - bcast[0]) * bcast[1] * gam[tid] + bet[tid];
    out[NB * NKP * 3 + (b * NKP + k) * NF + tid] = o;
}

extern "C" void kernel_launch(void* const* d_in, const int* in_sizes, int n_in,
                              void* d_out, int out_size, void* d_ws, size_t ws_size,
                              hipStream_t stream) {
    const float* h_rec = (const float*)d_in[0];
    const float* x_rec = (const float*)d_in[1];
    const float* h0_kp = (const float*)d_in[2];
    const float* W_src = (const float*)d_in[3];
    const float* W_mlp = (const float*)d_in[4];
    const float* b_mlp = (const float*)d_in[5];
    const float* gam   = (const float*)d_in[6];
    const float* bet   = (const float*)d_in[7];
    float* outp = (float*)d_out;
    float* ws = (float*)d_ws;

    float* ft = ws + FT_OFF;
    float* M  = ws + M_OFF;
    float* P  = ws + P_OFF;

    hipLaunchKernelGGL(k1_ftdst, dim3(320), dim3(256), 0, stream, h0_kp, W_src, ft);
    hipLaunchKernelGGL(k2_m,     dim3(320), dim3(256), 0, stream, ft, W_src, M);
    hipLaunchKernelGGL(k3_scores, dim3(256), dim3(512), 0, stream, h_rec, x_rec, M, P);
    hipLaunchKernelGGL(k4_final, dim3(160), dim3(256), 0, stream,
                       h_rec, x_rec, P, W_mlp, b_mlp, gam, bet, outp);
}

// Round 2
// 195.458 us; speedup vs baseline: 1.2833x; 1.2833x over previous
//
#include <hip/hip_runtime.h>
#include <math.h>

// Problem constants
static constexpr int NB  = 8;      // batch
static constexpr int NRC = 4096;   // rec atoms
static constexpr int NKP = 20;     // keypoints
static constexpr int NF  = 256;    // features
static constexpr int NHD = 4;      // heads
static constexpr int DD  = 256;    // per-head dim
static constexpr int NKH = NKP * NHD;  // 80 fused (k,h), kh = k*4+h
static constexpr int KCL = 8;      // k-closest
static constexpr int NT  = 32;     // row tiles in K3 (4096/128)
static constexpr float SCALE = 0.0625f; // 1/sqrt(256)

// workspace layout (float offsets)
// WT [1024][256] at 0  (dead after k12; P aliases it)
// M  [8][80][256] at 262144
static constexpr int WT_OFF = 0;
static constexpr int M_OFF  = 262144;
static constexpr int P_OFF  = 0;   // P [8][32][80][4] = 81920 floats, aliases WT

// K0: WT[c][f] = W[f][c]   (W is [256 f][1024 c])
__global__ __launch_bounds__(256) void k0_transpose(const float* __restrict__ W,
                                                    float* __restrict__ WT) {
    __shared__ float tile[64][65];
    int c0 = (blockIdx.x & 15) * 64;
    int f0 = (blockIdx.x >> 4) * 64;
    int lx = threadIdx.x & 63, ly = threadIdx.x >> 6;
#pragma unroll
    for (int rr = 0; rr < 16; ++rr) {
        int fr = ly + rr * 4;
        tile[fr][lx] = W[(f0 + fr) * 1024 + c0 + lx];
    }
    __syncthreads();
#pragma unroll
    for (int rr = 0; rr < 16; ++rr) {
        int cr = ly + rr * 4;
        WT[(c0 + cr) * 256 + f0 + lx] = tile[lx][cr];
    }
}

// K12: fused ft_dst + M.  One block per (b, h, k-quint).
// phase1: ft[k][d] = sum_g h0[b,k0+k,g] * W[g, h*256+d]      (thread = d)
// phase2: M[b, (k0+k)*4+h, f] = SCALE * sum_d W[f,h*256+d]*ft[k][d]
//         via WT (coalesced; thread = f)
__global__ __launch_bounds__(256) void k12_m(const float* __restrict__ h0,
                                             const float* __restrict__ W,
                                             const float* __restrict__ WT,
                                             float* __restrict__ M) {
    int bx = blockIdx.x;           // 8*4*4 = 128 blocks
    int b  = bx >> 4;
    int h  = (bx >> 2) & 3;
    int kq = bx & 3;
    int k0 = kq * 5;
    int tid = threadIdx.x;

    __shared__ float h0l[5][256];
    __shared__ float ftl[5][256];
#pragma unroll
    for (int k = 0; k < 5; ++k)
        h0l[k][tid] = h0[(b * NKP + k0 + k) * NF + tid];
    __syncthreads();

    // phase 1
    {
        float a0 = 0.f, a1 = 0.f, a2 = 0.f, a3 = 0.f, a4 = 0.f;
        const float* wp = W + h * DD + tid;
#pragma unroll 2
        for (int g4 = 0; g4 < 64; ++g4) {
            float4 hk0 = *(const float4*)&h0l[0][g4 * 4];
            float4 hk1 = *(const float4*)&h0l[1][g4 * 4];
            float4 hk2 = *(const float4*)&h0l[2][g4 * 4];
            float4 hk3 = *(const float4*)&h0l[3][g4 * 4];
            float4 hk4 = *(const float4*)&h0l[4][g4 * 4];
#pragma unroll
            for (int j = 0; j < 4; ++j) {
                float w = wp[(g4 * 4 + j) * 1024];
                a0 += w * ((const float*)&hk0)[j];
                a1 += w * ((const float*)&hk1)[j];
                a2 += w * ((const float*)&hk2)[j];
                a3 += w * ((const float*)&hk3)[j];
                a4 += w * ((const float*)&hk4)[j];
            }
        }
        ftl[0][tid] = a0; ftl[1][tid] = a1; ftl[2][tid] = a2;
        ftl[3][tid] = a3; ftl[4][tid] = a4;
    }
    __syncthreads();

    // phase 2
    float m0 = 0.f, m1 = 0.f, m2 = 0.f, m3 = 0.f, m4 = 0.f;
    const float* wtp = WT + (h * DD) * NF + tid;
#pragma unroll 2
    for (int d4 = 0; d4 < 64; ++d4) {
        float4 f0v = *(const float4*)&ftl[0][d4 * 4];
        float4 f1v = *(const float4*)&ftl[1][d4 * 4];
        float4 f2v = *(const float4*)&ftl[2][d4 * 4];
        float4 f3v = *(const float4*)&ftl[3][d4 * 4];
        float4 f4v = *(const float4*)&ftl[4][d4 * 4];
#pragma unroll
        for (int j = 0; j < 4; ++j) {
            float wt = wtp[(d4 * 4 + j) * 256];
            m0 += wt * ((const float*)&f0v)[j];
            m1 += wt * ((const float*)&f1v)[j];
            m2 += wt * ((const float*)&f2v)[j];
            m3 += wt * ((const float*)&f3v)[j];
            m4 += wt * ((const float*)&f4v)[j];
        }
    }
    M[(b * NKH + (k0 + 0) * NHD + h) * NF + tid] = m0 * SCALE;
    M[(b * NKH + (k0 + 1) * NHD + h) * NF + tid] = m1 * SCALE;
    M[(b * NKH + (k0 + 2) * NHD + h) * NF + tid] = m2 * SCALE;
    M[(b * NKH + (k0 + 3) * NHD + h) * NF + tid] = m3 * SCALE;
    M[(b * NKH + (k0 + 4) * NHD + h) * NF + tid] = m4 * SCALE;
}

// K3: scores + exp + weighted partial sums, M staged in LDS.
// grid 256 = (b, tile of 128 rows); 512 threads: wave q = tid>>6 owns cols
// q*10..q*10+9; lane owns rows (t*128 + lane*2, +1).
__global__ __launch_bounds__(512) void k3_scores(const float* __restrict__ hrec,
                                                 const float* __restrict__ xrec,
                                                 const float* __restrict__ Mg,
                                                 float* __restrict__ P) {
    extern __shared__ float Ml[];  // [256 f][80 kh] = 80 KB
    int bx = blockIdx.x;
    int b = bx >> 5, t = bx & 31;
    int tid = threadIdx.x;

    // stage M[b]: global [kh][f] -> LDS [f][kh]
    const float4* Mg4 = (const float4*)(Mg + b * NKH * NF);
    for (int i = tid; i < NKH * NF / 4; i += 512) {
        float4 v = Mg4[i];
        int kh = i >> 6;
        int f4 = (i & 63) * 4;
        Ml[(f4 + 0) * 80 + kh] = v.x;
        Ml[(f4 + 1) * 80 + kh] = v.y;
        Ml[(f4 + 2) * 80 + kh] = v.z;
        Ml[(f4 + 3) * 80 + kh] = v.w;
    }
    __syncthreads();

    int q = tid >> 6;
    int lane = tid & 63;
    int r0 = t * 128 + lane * 2;

    float acc0[10], acc1[10];
#pragma unroll
    for (int i = 0; i < 10; ++i) { acc0[i] = 0.f; acc1[i] = 0.f; }

    const float4* ha = (const float4*)(hrec + ((size_t)b * NRC + r0) * NF);
    const float4* hb = (const float4*)(hrec + ((size_t)b * NRC + r0 + 1) * NF);

#pragma unroll 2
    for (int f4 = 0; f4 < 64; ++f4) {
        float4 va = ha[f4], vb = hb[f4];
#pragma unroll
        for (int j = 0; j < 4; ++j) {
            int f = f4 * 4 + j;
            const float2* m2 = (const float2*)(Ml + f * 80 + q * 10);
            float A = ((const float*)&va)[j];
            float B = ((const float*)&vb)[j];
#pragma unroll
            for (int c2 = 0; c2 < 5; ++c2) {
                float2 mv = m2[c2];
                acc0[c2 * 2 + 0] += A * mv.x;
                acc0[c2 * 2 + 1] += A * mv.y;
                acc1[c2 * 2 + 0] += B * mv.x;
                acc1[c2 * 2 + 1] += B * mv.y;
            }
        }
    }

    const float* xa = xrec + ((size_t)b * NRC + r0) * 3;
    float x0 = xa[0], y0 = xa[1], z0 = xa[2];
    float x1 = xa[3], y1 = xa[4], z1 = xa[5];

    float s[10][4];
#pragma unroll
    for (int c = 0; c < 10; ++c) {
        float e0 = __expf(acc0[c]);
        float e1 = __expf(acc1[c]);
        s[c][0] = e0 + e1;
        s[c][1] = e0 * x0 + e1 * x1;
        s[c][2] = e0 * y0 + e1 * y1;
        s[c][3] = e0 * z0 + e1 * z1;
    }
#pragma unroll
    for (int c = 0; c < 10; ++c)
#pragma unroll
        for (int st = 0; st < 4; ++st)
#pragma unroll
            for (int m = 1; m < 64; m <<= 1)
                s[c][st] += __shfl_xor(s[c][st], m, 64);

    if (lane == 0) {
        float* Pp = P + ((size_t)(b * NT + t) * NKH + q * 10) * 4;
#pragma unroll
        for (int c = 0; c < 10; ++c)
#pragma unroll
            for (int st = 0; st < 4; ++st)
                Pp[c * 4 + st] = s[c][st];
    }
}

// K4: per (b,k): kp_pos, top-8 nearest rec atoms, knn feature mean, MLP+SiLU, LN.
__global__ __launch_bounds__(256) void k4_final(const float* __restrict__ hrec,
                                                const float* __restrict__ xrec,
                                                const float* __restrict__ P,
                                                const float* __restrict__ Wm,
                                                const float* __restrict__ bm,
                                                const float* __restrict__ gam,
                                                const float* __restrict__ bet,
                                                float* __restrict__ out) {
    int bx = blockIdx.x;
    int b = bx / NKP, k = bx % NKP;
    int tid = threadIdx.x;

    __shared__ float Sh[NHD][4];
    __shared__ float posl[3];
    __shared__ float d2[NRC];
    __shared__ float fin[NF + KCL];
    __shared__ int kidx[KCL];
    __shared__ float cd[4];
    __shared__ int ci[4];
    __shared__ float bcast[2];
    __shared__ float wred[4][2];

    if (tid < 16) {
        int h = tid >> 2, s = tid & 3;
        float a = 0.f;
#pragma unroll 4
        for (int t = 0; t < NT; ++t)
            a += P[((b * NT + t) * NKH + k * NHD + h) * 4 + s];
        Sh[h][s] = a;
    }
    __syncthreads();
    if (tid == 0) {
        for (int c = 0; c < 3; ++c) {
            float p = 0.f;
            for (int h = 0; h < NHD; ++h) p += Sh[h][c + 1] / Sh[h][0];
            p *= 0.25f;
            posl[c] = p;
            out[(b * NKP + k) * 3 + c] = p;
        }
    }
    __syncthreads();

    float px = posl[0], py = posl[1], pz = posl[2];
    for (int i = tid; i < NRC; i += 256) {
        const float* x = xrec + (size_t)(b * NRC + i) * 3;
        float dx = x[0] - px, dy = x[1] - py, dz = x[2] - pz;
        d2[i] = dx * dx + dy * dy + dz * dz;
    }
    __syncthreads();

    for (int j = 0; j < KCL; ++j) {
        float bd = 3.4e38f;
        int bi = -1;
        for (int i = tid; i < NRC; i += 256) {
            float v = d2[i];
            if (v < bd || (v == bd && i < bi)) { bd = v; bi = i; }
        }
        for (int off = 32; off >= 1; off >>= 1) {
            float od = __shfl_down(bd, off, 64);
            int oi = __shfl_down(bi, off, 64);
            if (od < bd || (od == bd && oi < bi)) { bd = od; bi = oi; }
        }
        if ((tid & 63) == 0) { cd[tid >> 6] = bd; ci[tid >> 6] = bi; }
        __syncthreads();
        if (tid == 0) {
            for (int w = 1; w < 4; ++w) {
                if (cd[w] < bd || (cd[w] == bd && ci[w] < bi)) { bd = cd[w]; bi = ci[w]; }
            }
            kidx[j] = bi;
            fin[NF + j] = sqrtf(bd);
            d2[bi] = 3.4e38f;
        }
        __syncthreads();
    }

    // knn feature mean
    float hm = 0.f;
#pragma unroll
    for (int j = 0; j < KCL; ++j)
        hm += hrec[(size_t)(b * NRC + kidx[j]) * NF + tid];
    fin[tid] = hm * 0.125f;
    __syncthreads();

    // MLP (264 -> 256) + SiLU
    float p = bm[tid];
#pragma unroll 4
    for (int i = 0; i < NF + KCL; ++i)
        p += fin[i] * Wm[i * NF + tid];
    float v = p / (1.f + __expf(-p));

    // LayerNorm over 256
    float s = v, sq = v * v;
#pragma unroll
    for (int m = 1; m < 64; m <<= 1) {
        s += __shfl_xor(s, m, 64);
        sq += __shfl_xor(sq, m, 64);
    }
    if ((tid & 63) == 0) { wred[tid >> 6][0] = s; wred[tid >> 6][1] = sq; }
    __syncthreads();
    if (tid == 0) {
        float ts = 0.f, tq = 0.f;
        for (int w = 0; w < 4; ++w) { ts += wred[w][0]; tq += wred[w][1]; }
        float mu = ts / 256.f;
        float var = tq / 256.f - mu * mu;
        bcast[0] = mu;
        bcast[1] = rsqrtf(var + 1e-5f);
    }
    __syncthreads();
    float o = (v - bcast[0]) * bcast[1] * gam[tid] + bet[tid];
    out[NB * NKP * 3 + (b * NKP + k) * NF + tid] = o;
}

extern "C" void kernel_launch(void* const* d_in, const int* in_sizes, int n_in,
                              void* d_out, int out_size, void* d_ws, size_t ws_size,
                              hipStream_t stream) {
    const float* h_rec = (const float*)d_in[0];
    const float* x_rec = (const float*)d_in[1];
    const float* h0_kp = (const float*)d_in[2];
    const float* W_src = (const float*)d_in[3];
    const float* W_mlp = (const float*)d_in[4];
    const float* b_mlp = (const float*)d_in[5];
    const float* gam   = (const float*)d_in[6];
    const float* bet   = (const float*)d_in[7];
    float* outp = (float*)d_out;
    float* ws = (float*)d_ws;

    float* WT = ws + WT_OFF;
    float* M  = ws + M_OFF;
    float* P  = ws + P_OFF;   // aliases WT (dead after k12)

    // allow 80 KB dynamic LDS for k3 (ignore error if unsupported)
    (void)hipFuncSetAttribute((const void*)k3_scores,
                              hipFuncAttributeMaxDynamicSharedMemorySize, 81920);

    hipLaunchKernelGGL(k0_transpose, dim3(64), dim3(256), 0, stream, W_src, WT);
    hipLaunchKernelGGL(k12_m, dim3(128), dim3(256), 0, stream, h0_kp, W_src, WT, M);
    hipLaunchKernelGGL(k3_scores, dim3(256), dim3(512), 81920, stream,
                       h_rec, x_rec, M, P);
    hipLaunchKernelGGL(k4_final, dim3(160), dim3(256), 0, stream,
                       h_rec, x_rec, P, W_mlp, b_mlp, gam, bet, outp);
}